// Round 7
// baseline (611.006 us; speedup 1.0000x reference)
//
#include <hip/hip_runtime.h>
#include <hip/hip_fp16.h>

typedef __attribute__((ext_vector_type(2))) int i32x2;

#define HH 1024
#define ROWP 512                   // pixel-pairs per row
#define NBLK 256                   // 1 block/CU -> co-resident
#define TPB 512
#define NSYNC 50                   // 2 Jacobi steps per sync
#define BOUNDARY_F 0.1f
#define TOKB 0x5A                  // per-wave flag byte
#define FLAGS_N (NSYNC * NBLK)     // 8B flag words (one byte per wave)

union h2u { __half2 h; int i; };

__device__ __forceinline__ i32x2 pack4(float4 v) {     // fp32x4 -> fp16x4 (RNE)
    h2u a, b;
    a.h = __float22half2_rn(make_float2(v.x, v.y));
    b.h = __float22half2_rn(make_float2(v.z, v.w));
    i32x2 r; r.x = a.i; r.y = b.i;
    return r;
}
__device__ __forceinline__ float4 unpack4(i32x2 p) {
    h2u a, b; a.i = p.x; b.i = p.y;
    float2 lo = __half22float2(a.h);
    float2 hi = __half22float2(b.h);
    return make_float4(lo.x, lo.y, hi.x, hi.y);
}
__device__ __forceinline__ float2 uph2(int u) {
    h2u x; x.i = u; return __half22float2(x.h);
}

// coherent 8B store: single fabric transaction, bypasses non-coherent L2
__device__ __forceinline__ void cst8(i32x2* base, int elem, i32x2 val) {
    asm volatile("global_store_dwordx2 %0, %1, %2 sc0 sc1"
                 :: "v"(elem * 8), "v"(val), "s"(base) : "memory");
}
// coherent 8B load (elem index); results must pass through wait8m before use
__device__ __forceinline__ i32x2 cld8(const i32x2* base, int elem) {
    i32x2 t;
    asm volatile("global_load_dwordx2 %0, %1, %2 sc0 sc1"
                 : "=v"(t) : "v"(elem * 8), "s"(base) : "memory");
    return t;
}
// coherent 4B load (byte offset) -- halo half-pairs
__device__ __forceinline__ int cld4b(const void* base, int byteoff) {
    int t;
    asm volatile("global_load_dword %0, %1, %2 sc0 sc1"
                 : "=v"(t) : "v"(byteoff), "s"(base) : "memory");
    return t;
}
// coherent byte store -- per-wave flag bytes
__device__ __forceinline__ void cstb(void* base, int byteoff, int val) {
    asm volatile("global_store_byte %0, %1, %2 sc0 sc1"
                 :: "v"(byteoff), "v"(val), "s"(base) : "memory");
}
// s_waitcnt with loaded registers as in/out operands: all later uses have a
// data dependency THROUGH the waitcnt (round-12-verified hazard fix).
__device__ __forceinline__ void wait8m(i32x2& a, i32x2& b, i32x2& c, i32x2& d,
                                       int& e, int& f, int& g, int& h) {
    asm volatile("s_waitcnt vmcnt(0)"
                 : "+v"(a), "+v"(b), "+v"(c), "+v"(d),
                   "+v"(e), "+v"(f), "+v"(g), "+v"(h) :: "memory");
}
// per-wave drain; ALSO ties the rolling-poll scratch regs so any probe loads
// still in flight from poll8's early exit land into live (never-read) regs.
__device__ __forceinline__ void drain4(int& a, int& b, int& c, int& d) {
    asm volatile("s_waitcnt vmcnt(0)"
                 : "+v"(a), "+v"(b), "+v"(c), "+v"(d) :: "memory");
}

// 2-deep ROLLING poll of an 8B flag word (two dwords) by a SINGLE lane.
// Two probe pairs in flight; oldest pair checked while newer flies -> probe
// period ~RT/2 instead of RT. Exits WITHOUT draining (caller ties a0..b1
// into the next vmcnt(0) via drain4). Guard bounds worst-case spin.
__device__ __forceinline__ void poll8(const void* base, int byteoff,
                                      int& a0, int& b0, int& a1, int& b1) {
    unsigned gt;
    asm volatile(
        "global_load_dword %[a0], %[off], %[srd] sc0 sc1\n\t"
        "global_load_dword %[b0], %[off4], %[srd] sc0 sc1\n\t"
        "global_load_dword %[a1], %[off], %[srd] sc0 sc1\n\t"
        "global_load_dword %[b1], %[off4], %[srd] sc0 sc1\n\t"
        "s_movk_i32 %[g], 0x7fff\n\t"
        "Lp%=:\n\t"
        "s_waitcnt vmcnt(2)\n\t"                       // pair0 landed
        "v_cmp_eq_u32 vcc, 0x5a5a5a5a, %[a0]\n\t"
        "s_cbranch_vccz Lr0%=\n\t"
        "v_cmp_eq_u32 vcc, 0x5a5a5a5a, %[b0]\n\t"
        "s_cbranch_vccnz Ld%=\n\t"
        "Lr0%=:\n\t"
        "global_load_dword %[a0], %[off], %[srd] sc0 sc1\n\t"
        "global_load_dword %[b0], %[off4], %[srd] sc0 sc1\n\t"
        "s_sub_i32 %[g], %[g], 1\n\t"
        "s_cmp_lt_i32 %[g], 1\n\t"
        "s_cbranch_scc1 Ld%=\n\t"
        "s_waitcnt vmcnt(2)\n\t"                       // pair1 landed
        "v_cmp_eq_u32 vcc, 0x5a5a5a5a, %[a1]\n\t"
        "s_cbranch_vccz Lr1%=\n\t"
        "v_cmp_eq_u32 vcc, 0x5a5a5a5a, %[b1]\n\t"
        "s_cbranch_vccnz Ld%=\n\t"
        "Lr1%=:\n\t"
        "global_load_dword %[a1], %[off], %[srd] sc0 sc1\n\t"
        "global_load_dword %[b1], %[off4], %[srd] sc0 sc1\n\t"
        "s_branch Lp%=\n\t"
        "Ld%=:\n\t"
        : [a0]"+v"(a0), [b0]"+v"(b0), [a1]"+v"(a1), [b1]"+v"(b1), [g]"=&s"(gt)
        : [off]"v"(byteoff), [off4]"v"(byteoff + 4), [srd]"s"(base)
        : "vcc", "memory");
}

__device__ __forceinline__ float wfun(float c, float n, float valid) {
    float same = ((c > BOUNDARY_F) != (n > BOUNDARY_F)) ? 1.0f : 0.0f;
    return valid * __expf(-fabsf(c - n + same));
}

// Jacobi update of one pixel-pair; w = {w0u,w0d,w0l,w0r, w1u,w1d,w1l,w1r}
__device__ __forceinline__ float4 stepr(const float* w, bool m0, bool m1,
                                        float4 xc, float4 xu, float4 xd,
                                        float2 xl, float2 xr) {
    float4 o;
    o.x = w[0]*xu.x + w[1]*xd.x + w[2]*xl.x + w[3]*xc.z;
    o.y = w[0]*xu.y + w[1]*xd.y + w[2]*xl.y + w[3]*xc.w;
    o.z = w[4]*xu.z + w[5]*xd.z + w[6]*xc.x + w[7]*xr.x;
    o.w = w[4]*xu.w + w[5]*xd.w + w[6]*xc.y + w[7]*xr.y;
    if (m0) { o.x = xc.x; o.y = xc.y; }     // absorbing seeds
    if (m1) { o.z = xc.z; o.w = xc.w; }
    return o;
}
// 3-term partials (computed in the ghost-load shadow) + ghost-term finishers
__device__ __forceinline__ float4 part_noxu(const float* w, float4 xc, float4 xd,
                                            float2 xl, float2 xr) {
    float4 p;
    p.x = w[1]*xd.x + w[2]*xl.x + w[3]*xc.z;
    p.y = w[1]*xd.y + w[2]*xl.y + w[3]*xc.w;
    p.z = w[5]*xd.z + w[6]*xc.x + w[7]*xr.x;
    p.w = w[5]*xd.w + w[6]*xc.y + w[7]*xr.y;
    return p;
}
__device__ __forceinline__ float4 fin_xu(const float* w, bool m0, bool m1,
                                         float4 p, float4 xu, float4 xc) {
    float4 o;
    o.x = p.x + w[0]*xu.x;  o.y = p.y + w[0]*xu.y;
    o.z = p.z + w[4]*xu.z;  o.w = p.w + w[4]*xu.w;
    if (m0) { o.x = xc.x; o.y = xc.y; }
    if (m1) { o.z = xc.z; o.w = xc.w; }
    return o;
}
__device__ __forceinline__ float4 part_noxd(const float* w, float4 xc, float4 xu,
                                            float2 xl, float2 xr) {
    float4 p;
    p.x = w[0]*xu.x + w[2]*xl.x + w[3]*xc.z;
    p.y = w[0]*xu.y + w[2]*xl.y + w[3]*xc.w;
    p.z = w[4]*xu.z + w[6]*xc.x + w[7]*xr.x;
    p.w = w[4]*xu.w + w[6]*xc.y + w[7]*xr.y;
    return p;
}
__device__ __forceinline__ float4 fin_xd(const float* w, bool m0, bool m1,
                                         float4 p, float4 xd, float4 xc) {
    float4 o;
    o.x = p.x + w[1]*xd.x;  o.y = p.y + w[1]*xd.y;
    o.z = p.z + w[5]*xd.z;  o.w = p.w + w[5]*xd.w;
    if (m0) { o.x = xc.x; o.y = xc.y; }
    if (m1) { o.z = xc.z; o.w = xc.w; }
    return o;
}

__device__ __forceinline__ void horiz(const float4* row, int tid, float4 xc,
                                      float2* xl, float2* xr) {
    const float2* r2 = (const float2*)row;
    *xl = (tid > 0) ? r2[2 * tid - 1] : make_float2(xc.x, xc.y);
    *xr = (tid < ROWP - 1) ? r2[2 * tid + 2] : make_float2(xc.z, xc.w);
}

// zero all flag bytes (FLAGS_N 8-byte words): every launch self-contained
__global__ void rw_init_kernel(unsigned* __restrict__ flags) {
    int g = blockIdx.x * blockDim.x + threadIdx.x;
    if (g < FLAGS_N * 2) flags[g] = 0u;
}

__launch_bounds__(TPB)
__global__ void rw_persist_kernel(const float* __restrict__ img,
                                  const int* __restrict__ seeds,
                                  float4* __restrict__ out4,   // d_out fp32, final only
                                  i32x2* __restrict__ parE,    // ws: fp16 x_{2m}, m even
                                  i32x2* __restrict__ parO,    // ws: fp16 x_{2m}, m odd
                                  unsigned long long* __restrict__ flags8) {
    const int tid = threadIdx.x;
    const int blk = blockIdx.x;
    const int band = ((blk & 7) << 5) | (blk >> 3);   // XCD swizzle (perf only)
    const int i0 = band * 4;

    // S[0..3]: own x rows i0..i0+3 horiz copies; S[4..7]: y1..y4 horiz.
    // Ghost rows no longer staged in LDS (direct halo dword loads) -> 64 KB.
    __shared__ float4 S[8][ROWP];

    // ---- iteration-invariant weights + masks for rows i0-1..i0+4 ----
    float cfv[6][8];
    unsigned mb0 = 0, mb1 = 0;
    float4 s0, s1, s2, s3;                            // register-resident band
    {
        const float2* img2 = (const float2*)img;
        const int2* seeds2 = (const int2*)seeds;
#pragma unroll
        for (int L = 0; L < 6; ++L) {
            const int g = min(max(i0 - 1 + L, 0), HH - 1);
            const int P = g * ROWP + tid;
            const int p = P * 2;
            const int j = p & 1023;
            const int uP = (g > 0) ? P - ROWP : P;
            const int dP = (g < HH - 1) ? P + ROWP : P;
            const int lp = (j > 0) ? p - 1 : p;
            const int rp = (j < 1022) ? p + 2 : p + 1;

            float2 cc = img2[P], iu = img2[uP], id = img2[dP];
            float il = img[lp], ir = img[rp];
            const float vU = (g > 0) ? 1.0f : 0.0f;
            const float vD = (g < HH - 1) ? 1.0f : 0.0f;
            const float vL = (j > 0) ? 1.0f : 0.0f;
            const float vR = (j < 1022) ? 1.0f : 0.0f;

            float w0u = wfun(cc.x, iu.x, vU), w0d = wfun(cc.x, id.x, vD);
            float w0l = wfun(cc.x, il, vL),   w0r = wfun(cc.x, cc.y, 1.0f);
            float rs0 = w0u + w0d + w0l + w0r;
            float inv0 = (rs0 > 0.0f) ? 1.0f / rs0 : 0.0f;
            float w1u = wfun(cc.y, iu.y, vU), w1d = wfun(cc.y, id.y, vD);
            float w1l = wfun(cc.y, cc.x, 1.0f), w1r = wfun(cc.y, ir, vR);
            float rs1 = w1u + w1d + w1l + w1r;
            float inv1 = (rs1 > 0.0f) ? 1.0f / rs1 : 0.0f;

            cfv[L][0] = w0u * inv0; cfv[L][1] = w0d * inv0;
            cfv[L][2] = w0l * inv0; cfv[L][3] = w0r * inv0;
            cfv[L][4] = w1u * inv1; cfv[L][5] = w1d * inv1;
            cfv[L][6] = w1l * inv1; cfv[L][7] = w1r * inv1;

            int2 s = seeds2[P];
            if (s.x > 0) mb0 |= 1u << L;
            if (s.y > 0) mb1 |= 1u << L;
            if (L >= 1 && L <= 4) {
                float4 v;
                v.x = (s.x == 1) ? 1.0f : 0.0f;
                v.y = (s.x == 2) ? 1.0f : 0.0f;
                v.z = (s.y == 1) ? 1.0f : 0.0f;
                v.w = (s.y == 2) ? 1.0f : 0.0f;
                if (L == 1) s0 = v; else if (L == 2) s1 = v;
                else if (L == 3) s2 = v; else s3 = v;
            }
        }
    }

    // rolling-poll scratch (waves 0/1 use them; tied into every drain4)
    int qa0 = 0, qb0 = 0, qa1 = 0, qb1 = 0;

    // ---- publish x0 (fp16) -> parE + seed LDS horiz copies; per-wave flag ----
    S[0][tid] = s0; S[1][tid] = s1;
    S[2][tid] = s2; S[3][tid] = s3;
    cst8(parE, (i0 + 0) * ROWP + tid, pack4(s0));
    cst8(parE, (i0 + 1) * ROWP + tid, pack4(s1));
    cst8(parE, (i0 + 2) * ROWP + tid, pack4(s2));
    cst8(parE, (i0 + 3) * ROWP + tid, pack4(s3));
    drain4(qa0, qb0, qa1, qb1);                       // own publishes drained
    if ((tid & 63) == 0)                              // one byte per wave
        cstb((void*)flags8, band * 8 + (tid >> 6), TOKB);

    // ghost row indices (clamped; clamped rows get weight 0 on real rows)
    const int gU2 = max(i0 - 2, 0), gU1 = max(i0 - 1, 0);
    const int gD0 = min(i0 + 4, HH - 1), gD1 = min(i0 + 5, HH - 1);
    const int eU1 = gU1 * ROWP, eD0 = gD0 * ROWP;
    // halo dword byte-offsets (left = hi half of pair tid-1, right = lo half
    // of pair tid+1); tid edges clamp to own pair (value discarded below)
    const int offBl = (tid > 0)        ? (eU1 + tid) * 8 - 4   : eU1 * 8;
    const int offBr = (tid < ROWP - 1) ? (eU1 + tid + 1) * 8   : (eU1 + tid) * 8;
    const int offCl = (tid > 0)        ? (eD0 + tid) * 8 - 4   : eD0 * 8;
    const int offCr = (tid < ROWP - 1) ? (eD0 + tid + 1) * 8   : (eD0 + tid) * 8;

    for (int m = 0; m < NSYNC; ++m) {
        // ---- rolling polls: tid0 watches up word, tid64 watches down word ----
        if (band > 0 && tid == 0)
            poll8((const void*)flags8, (m * NBLK + band - 1) * 8,
                  qa0, qb0, qa1, qb1);
        if (band < NBLK - 1 && tid == 64)
            poll8((const void*)flags8, (m * NBLK + band + 1) * 8,
                  qa0, qb0, qa1, qb1);
        __syncthreads();                              // [A]
        asm volatile("" ::: "memory");

        const i32x2* pin = (m & 1) ? parO : parE;

        // ---- issue ghost pair loads + halo dwords (coherent) ----
        i32x2 rA = cld8(pin, gU2 * ROWP + tid);       // row i0-2 (vertical only)
        i32x2 rB = cld8(pin, eU1 + tid);              // row i0-1
        i32x2 rC = cld8(pin, eD0 + tid);              // row i0+4
        i32x2 rD = cld8(pin, gD1 * ROWP + tid);       // row i0+5 (vertical only)
        int hBl = cld4b(pin, offBl);                  // U1 left half-pair
        int hBr = cld4b(pin, offBr);                  // U1 right half-pair
        int hCl = cld4b(pin, offCl);                  // D0 left half-pair
        int hCr = cld4b(pin, offCr);                  // D0 right half-pair

        // ---- shadow: y2,y3 full + y1,y4 3-term partials while loads fly ----
        float2 xl, xr;
        horiz(&S[1][0], tid, s1, &xl, &xr);
        float4 y2 = stepr(cfv[2], (mb0 >> 2) & 1, (mb1 >> 2) & 1, s1, s0, s2, xl, xr);
        horiz(&S[2][0], tid, s2, &xl, &xr);
        float4 y3 = stepr(cfv[3], (mb0 >> 3) & 1, (mb1 >> 3) & 1, s2, s1, s3, xl, xr);
        S[5][tid] = y2;
        S[6][tid] = y3;
        horiz(&S[0][0], tid, s0, &xl, &xr);
        float4 p1 = part_noxu(cfv[1], s0, s1, xl, xr);   // y1 minus ghost xu term
        horiz(&S[3][0], tid, s3, &xl, &xr);
        float4 p4 = part_noxd(cfv[4], s3, s2, xl, xr);   // y4 minus ghost xd term

        wait8m(rA, rB, rC, rD, hBl, hBr, hCl, hCr);   // loads landed; deps tied
        float4 vU2 = unpack4(rA);
        float4 vU1 = unpack4(rB);
        float4 vD0 = unpack4(rC);
        float4 vD1 = unpack4(rD);

        float4 y1 = fin_xu(cfv[1], (mb0 >> 1) & 1, (mb1 >> 1) & 1, p1, vU1, s0);
        float4 y4 = fin_xd(cfv[4], (mb0 >> 4) & 1, (mb1 >> 4) & 1, p4, vD0, s3);
        // y0/y5 horiz from direct-loaded halos (no LDS, no barrier [B])
        float2 bl = (tid > 0)        ? uph2(hBl) : make_float2(vU1.x, vU1.y);
        float2 br = (tid < ROWP - 1) ? uph2(hBr) : make_float2(vU1.z, vU1.w);
        float4 y0 = stepr(cfv[0], (mb0 >> 0) & 1, (mb1 >> 0) & 1, vU1, vU2, s0, bl, br);
        float2 cl = (tid > 0)        ? uph2(hCl) : make_float2(vD0.x, vD0.y);
        float2 cr = (tid < ROWP - 1) ? uph2(hCr) : make_float2(vD0.z, vD0.w);
        float4 y5 = stepr(cfv[5], (mb0 >> 5) & 1, (mb1 >> 5) & 1, vD0, s3, vD1, cl, cr);
        S[4][tid] = y1;
        S[7][tid] = y4;
        __syncthreads();                              // [C]

        // ---- step 2, own rows; publish each o row the moment it exists ----
        i32x2* pout = (m & 1) ? parE : parO;
        const bool last = (m == NSYNC - 1);

        horiz(&S[4][0], tid, y1, &xl, &xr);
        float4 o0 = stepr(cfv[1], (mb0 >> 1) & 1, (mb1 >> 1) & 1, y1, y0, y2, xl, xr);
        if (!last) cst8(pout, (i0 + 0) * ROWP + tid, pack4(o0));
        horiz(&S[5][0], tid, y2, &xl, &xr);
        float4 o1 = stepr(cfv[2], (mb0 >> 2) & 1, (mb1 >> 2) & 1, y2, y1, y3, xl, xr);
        if (!last) cst8(pout, (i0 + 1) * ROWP + tid, pack4(o1));
        horiz(&S[6][0], tid, y3, &xl, &xr);
        float4 o2 = stepr(cfv[3], (mb0 >> 3) & 1, (mb1 >> 3) & 1, y3, y2, y4, xl, xr);
        if (!last) cst8(pout, (i0 + 2) * ROWP + tid, pack4(o2));
        horiz(&S[7][0], tid, y4, &xl, &xr);
        float4 o3 = stepr(cfv[4], (mb0 >> 4) & 1, (mb1 >> 4) & 1, y4, y3, y5, xl, xr);
        if (!last) cst8(pout, (i0 + 3) * ROWP + tid, pack4(o3));

        if (last) {
            // x_100 -> d_out fp32 (never read by any block: race-free)
            out4[(i0 + 0) * ROWP + tid] = o0;
            out4[(i0 + 1) * ROWP + tid] = o1;
            out4[(i0 + 2) * ROWP + tid] = o2;
            out4[(i0 + 3) * ROWP + tid] = o3;
            drain4(qa0, qb0, qa1, qb1);   // no pending probe loads at endpgm
            break;
        }

        // ---- per-wave drain + per-wave flag byte (no [D] barrier): the
        // consumer needs all 8 bytes, so readiness = max over waves, same as
        // before minus the barrier and the cross-wave drain coupling ----
        drain4(qa0, qb0, qa1, qb1);
        if ((tid & 63) == 0)
            cstb((void*)flags8, ((m + 1) * NBLK + band) * 8 + (tid >> 6), TOKB);

        // ---- off-chain: LDS writeback + register rotation (ordered vs next
        // sync's reads by barrier [A]) ----
        S[0][tid] = o0; S[1][tid] = o1;
        S[2][tid] = o2; S[3][tid] = o3;
        s0 = o0; s1 = o1; s2 = o2; s3 = o3;
    }
}

extern "C" void kernel_launch(void* const* d_in, const int* in_sizes, int n_in,
                              void* d_out, int out_size, void* d_ws, size_t ws_size,
                              hipStream_t stream) {
    const float* img = (const float*)d_in[0];
    const int* seeds = (const int*)d_in[1];

    float4* out4 = (float4*)d_out;                              // fp32 final only
    char* ws = (char*)d_ws;
    i32x2* parE = (i32x2*)ws;                                   // 4 MB fp16 even parity
    i32x2* parO = (i32x2*)(ws + 4ull * 1024 * 1024);            // 4 MB fp16 odd parity
    unsigned long long* flags8 =
        (unsigned long long*)(ws + 8ull * 1024 * 1024);         // 102.4 KB flag words

    rw_init_kernel<<<(FLAGS_N * 2 + 255) / 256, 256, 0, stream>>>((unsigned*)flags8);
    rw_persist_kernel<<<NBLK, TPB, 0, stream>>>(img, seeds, out4, parE, parO, flags8);
}

// Round 8
// 239.180 us; speedup vs baseline: 2.5546x; 2.5546x over previous
//
#include <hip/hip_runtime.h>
#include <hip/hip_fp16.h>

typedef __attribute__((ext_vector_type(2))) int i32x2;

#define HH 1024
#define ROWP 512                   // pixel-pairs per row
#define NBLK 256                   // 1 block/CU -> co-resident
#define TPB 512
#define NSYNC 50                   // 2 Jacobi steps per sync
#define BOUNDARY_F 0.1f
#define TOKEN 0x5A5A5A5Au
#define FLAGS_N (NSYNC * NBLK)

union h2u { __half2 h; int i; };

__device__ __forceinline__ i32x2 pack4(float4 v) {     // fp32x4 -> fp16x4 (RNE)
    h2u a, b;
    a.h = __float22half2_rn(make_float2(v.x, v.y));
    b.h = __float22half2_rn(make_float2(v.z, v.w));
    i32x2 r; r.x = a.i; r.y = b.i;
    return r;
}
__device__ __forceinline__ float4 unpack4(i32x2 p) {
    h2u a, b; a.i = p.x; b.i = p.y;
    float2 lo = __half22float2(a.h);
    float2 hi = __half22float2(b.h);
    return make_float4(lo.x, lo.y, hi.x, hi.y);
}

// coherent 8B store: single fabric transaction, bypasses non-coherent L2
__device__ __forceinline__ void cst8(i32x2* base, int elem, i32x2 val) {
    asm volatile("global_store_dwordx2 %0, %1, %2 sc0 sc1"
                 :: "v"(elem * 8), "v"(val), "s"(base) : "memory");
}
// coherent 8B load; result MUST be passed through wait4 before any use
__device__ __forceinline__ i32x2 cld8(const i32x2* base, int elem) {
    i32x2 t;
    asm volatile("global_load_dwordx2 %0, %1, %2 sc0 sc1"
                 : "=v"(t) : "v"(elem * 8), "s"(base) : "memory");
    return t;
}
// s_waitcnt with loaded registers as in/out operands: all later uses have a
// data dependency THROUGH the waitcnt (round-12-verified hazard fix).
__device__ __forceinline__ void wait4(i32x2& a, i32x2& b, i32x2& c, i32x2& d) {
    asm volatile("s_waitcnt vmcnt(0)"
                 : "+v"(a), "+v"(b), "+v"(c), "+v"(d) :: "memory");
}
__device__ __forceinline__ void waitvm0() {
    asm volatile("s_waitcnt vmcnt(0)" ::: "memory");
}

__device__ __forceinline__ float wfun(float c, float n, float valid) {
    float same = ((c > BOUNDARY_F) != (n > BOUNDARY_F)) ? 1.0f : 0.0f;
    return valid * __expf(-fabsf(c - n + same));
}

// Jacobi update of one pixel-pair; w = {w0u,w0d,w0l,w0r, w1u,w1d,w1l,w1r}
__device__ __forceinline__ float4 stepr(const float* w, bool m0, bool m1,
                                        float4 xc, float4 xu, float4 xd,
                                        float2 xl, float2 xr) {
    float4 o;
    o.x = w[0]*xu.x + w[1]*xd.x + w[2]*xl.x + w[3]*xc.z;
    o.y = w[0]*xu.y + w[1]*xd.y + w[2]*xl.y + w[3]*xc.w;
    o.z = w[4]*xu.z + w[5]*xd.z + w[6]*xc.x + w[7]*xr.x;
    o.w = w[4]*xu.w + w[5]*xd.w + w[6]*xc.y + w[7]*xr.y;
    if (m0) { o.x = xc.x; o.y = xc.y; }     // absorbing seeds
    if (m1) { o.z = xc.z; o.w = xc.w; }
    return o;
}

__device__ __forceinline__ void horiz(const float4* row, int tid, float4 xc,
                                      float2* xl, float2* xr) {
    const float2* r2 = (const float2*)row;
    *xl = (tid > 0) ? r2[2 * tid - 1] : make_float2(xc.x, xc.y);
    *xr = (tid < ROWP - 1) ? r2[2 * tid + 2] : make_float2(xc.z, xc.w);
}

// zero all flag slots: every launch self-contained (round-16-verified fix)
__global__ void rw_init_kernel(unsigned* __restrict__ flags) {
    int g = blockIdx.x * blockDim.x + threadIdx.x;
    if (g < FLAGS_N) flags[g] = 0u;
}

__launch_bounds__(TPB)
__global__ void rw_persist_kernel(const float* __restrict__ img,
                                  const int* __restrict__ seeds,
                                  float4* __restrict__ out4,   // d_out fp32, final only
                                  i32x2* __restrict__ parE,    // ws: fp16 x_{2m}, m even
                                  i32x2* __restrict__ parO,    // ws: fp16 x_{2m}, m odd
                                  unsigned* __restrict__ flags) {
    const int tid = threadIdx.x;
    const int blk = blockIdx.x;
    const int band = ((blk & 7) << 5) | (blk >> 3);   // XCD swizzle (perf only)
    const int i0 = band * 4;

    // slots 0..5: x rows i0-1..i0+4 (horizontal copies, fp32); 6..9: y rows
    __shared__ float4 srows[10][ROWP];                // 80 KB

    // ---- iteration-invariant weights + masks for rows i0-1..i0+4 ----
    float cfv[6][8];
    unsigned mb0 = 0, mb1 = 0;
    float4 s0, s1, s2, s3;                            // register-resident band (fp32)
    {
        const float2* img2 = (const float2*)img;
        const int2* seeds2 = (const int2*)seeds;
#pragma unroll
        for (int L = 0; L < 6; ++L) {
            const int g = min(max(i0 - 1 + L, 0), HH - 1);
            const int P = g * ROWP + tid;
            const int p = P * 2;
            const int j = p & 1023;
            const int uP = (g > 0) ? P - ROWP : P;
            const int dP = (g < HH - 1) ? P + ROWP : P;
            const int lp = (j > 0) ? p - 1 : p;
            const int rp = (j < 1022) ? p + 2 : p + 1;

            float2 cc = img2[P], iu = img2[uP], id = img2[dP];
            float il = img[lp], ir = img[rp];
            const float vU = (g > 0) ? 1.0f : 0.0f;
            const float vD = (g < HH - 1) ? 1.0f : 0.0f;
            const float vL = (j > 0) ? 1.0f : 0.0f;
            const float vR = (j < 1022) ? 1.0f : 0.0f;

            float w0u = wfun(cc.x, iu.x, vU), w0d = wfun(cc.x, id.x, vD);
            float w0l = wfun(cc.x, il, vL),   w0r = wfun(cc.x, cc.y, 1.0f);
            float rs0 = w0u + w0d + w0l + w0r;
            float inv0 = (rs0 > 0.0f) ? 1.0f / rs0 : 0.0f;
            float w1u = wfun(cc.y, iu.y, vU), w1d = wfun(cc.y, id.y, vD);
            float w1l = wfun(cc.y, cc.x, 1.0f), w1r = wfun(cc.y, ir, vR);
            float rs1 = w1u + w1d + w1l + w1r;
            float inv1 = (rs1 > 0.0f) ? 1.0f / rs1 : 0.0f;

            cfv[L][0] = w0u * inv0; cfv[L][1] = w0d * inv0;
            cfv[L][2] = w0l * inv0; cfv[L][3] = w0r * inv0;
            cfv[L][4] = w1u * inv1; cfv[L][5] = w1d * inv1;
            cfv[L][6] = w1l * inv1; cfv[L][7] = w1r * inv1;

            int2 s = seeds2[P];
            if (s.x > 0) mb0 |= 1u << L;
            if (s.y > 0) mb1 |= 1u << L;
            if (L >= 1 && L <= 4) {
                float4 v;
                v.x = (s.x == 1) ? 1.0f : 0.0f;
                v.y = (s.x == 2) ? 1.0f : 0.0f;
                v.z = (s.y == 1) ? 1.0f : 0.0f;
                v.w = (s.y == 2) ? 1.0f : 0.0f;
                if (L == 1) s0 = v; else if (L == 2) s1 = v;
                else if (L == 3) s2 = v; else s3 = v;
            }
        }
    }

    // ---- publish x0 (fp16) -> parE + seed LDS horizontal copies ----
    srows[1][tid] = s0; srows[2][tid] = s1;
    srows[3][tid] = s2; srows[4][tid] = s3;
    cst8(parE, (i0 + 0) * ROWP + tid, pack4(s0));
    cst8(parE, (i0 + 1) * ROWP + tid, pack4(s1));
    cst8(parE, (i0 + 2) * ROWP + tid, pack4(s2));
    cst8(parE, (i0 + 3) * ROWP + tid, pack4(s3));
    waitvm0();
    __syncthreads();               // LDS visible + publish drained
    if (tid == 0)
        __hip_atomic_store(&flags[band], TOKEN, __ATOMIC_RELAXED,
                           __HIP_MEMORY_SCOPE_AGENT);

    const int gU2 = max(i0 - 2, 0), gU1 = max(i0 - 1, 0);
    const int gD0 = min(i0 + 4, HH - 1), gD1 = min(i0 + 5, HH - 1);

    for (int m = 0; m < NSYNC; ++m) {
        // ---- poll neighbors' x_{2m} flags (two waves in parallel, no backoff:
        // poll period = natural ~L3 load latency; relaxed loads, no cache ops) ----
        if (tid == 0 && band > 0) {
            int guard = 0;
            while (__hip_atomic_load(&flags[m * NBLK + band - 1], __ATOMIC_RELAXED,
                                     __HIP_MEMORY_SCOPE_AGENT) != TOKEN) {
                if (++guard > (1 << 22)) break;
            }
        }
        if (tid == 64 && band < NBLK - 1) {
            int guard = 0;
            while (__hip_atomic_load(&flags[m * NBLK + band + 1], __ATOMIC_RELAXED,
                                     __HIP_MEMORY_SCOPE_AGENT) != TOKEN) {
                if (++guard > (1 << 22)) break;
            }
        }
        __syncthreads();                              // [A]
        asm volatile("" ::: "memory");

        const i32x2* pin = (m & 1) ? parO : parE;

        // ---- issue 2-deep ghost row loads (coherent fp16 8B) ----
        i32x2 rA = cld8(pin, gU2 * ROWP + tid);       // row i0-2
        i32x2 rB = cld8(pin, gU1 * ROWP + tid);       // row i0-1
        i32x2 rC = cld8(pin, gD0 * ROWP + tid);       // row i0+4
        i32x2 rD = cld8(pin, gD1 * ROWP + tid);       // row i0+5

        // ---- step 1 interior rows (no ghost dep) while loads fly ----
        float2 xl, xr;
        horiz(&srows[2][0], tid, s1, &xl, &xr);
        float4 y2 = stepr(cfv[2], (mb0 >> 2) & 1, (mb1 >> 2) & 1, s1, s0, s2, xl, xr);
        horiz(&srows[3][0], tid, s2, &xl, &xr);
        float4 y3 = stepr(cfv[3], (mb0 >> 3) & 1, (mb1 >> 3) & 1, s2, s1, s3, xl, xr);
        srows[7][tid] = y2;
        srows[8][tid] = y3;

        wait4(rA, rB, rC, rD);                        // loads landed; deps tied
        float4 vU2 = unpack4(rA);
        float4 vU1 = unpack4(rB);
        float4 vD0 = unpack4(rC);
        float4 vD1 = unpack4(rD);
        srows[0][tid] = vU1;
        srows[5][tid] = vD0;
        __syncthreads();                              // [B]

        // ---- step 1 ghost-dependent rows ----
        horiz(&srows[0][0], tid, vU1, &xl, &xr);
        float4 y0 = stepr(cfv[0], (mb0 >> 0) & 1, (mb1 >> 0) & 1, vU1, vU2, s0, xl, xr);
        horiz(&srows[1][0], tid, s0, &xl, &xr);
        float4 y1 = stepr(cfv[1], (mb0 >> 1) & 1, (mb1 >> 1) & 1, s0, vU1, s1, xl, xr);
        horiz(&srows[4][0], tid, s3, &xl, &xr);
        float4 y4 = stepr(cfv[4], (mb0 >> 4) & 1, (mb1 >> 4) & 1, s3, s2, vD0, xl, xr);
        horiz(&srows[5][0], tid, vD0, &xl, &xr);
        float4 y5 = stepr(cfv[5], (mb0 >> 5) & 1, (mb1 >> 5) & 1, vD0, s3, vD1, xl, xr);
        srows[6][tid] = y1;
        srows[9][tid] = y4;
        __syncthreads();                              // [C]

        // ---- step 2, own rows; publish each o row the moment it exists ----
        i32x2* pout = (m & 1) ? parE : parO;
        const bool last = (m == NSYNC - 1);

        horiz(&srows[6][0], tid, y1, &xl, &xr);
        float4 o0 = stepr(cfv[1], (mb0 >> 1) & 1, (mb1 >> 1) & 1, y1, y0, y2, xl, xr);
        if (!last) cst8(pout, (i0 + 0) * ROWP + tid, pack4(o0));
        horiz(&srows[7][0], tid, y2, &xl, &xr);
        float4 o1 = stepr(cfv[2], (mb0 >> 2) & 1, (mb1 >> 2) & 1, y2, y1, y3, xl, xr);
        if (!last) cst8(pout, (i0 + 1) * ROWP + tid, pack4(o1));
        horiz(&srows[8][0], tid, y3, &xl, &xr);
        float4 o2 = stepr(cfv[3], (mb0 >> 3) & 1, (mb1 >> 3) & 1, y3, y2, y4, xl, xr);
        if (!last) cst8(pout, (i0 + 2) * ROWP + tid, pack4(o2));
        horiz(&srows[9][0], tid, y4, &xl, &xr);
        float4 o3 = stepr(cfv[4], (mb0 >> 4) & 1, (mb1 >> 4) & 1, y4, y3, y5, xl, xr);
        if (!last) cst8(pout, (i0 + 3) * ROWP + tid, pack4(o3));

        if (last) {
            // x_100 -> d_out fp32 (never read by any block: race-free)
            out4[(i0 + 0) * ROWP + tid] = o0;
            out4[(i0 + 1) * ROWP + tid] = o1;
            out4[(i0 + 2) * ROWP + tid] = o2;
            out4[(i0 + 3) * ROWP + tid] = o3;
            break;
        }

        waitvm0();                                    // each wave drains publishes
        __syncthreads();                              // [D] all waves drained
        if (tid == 0)
            __hip_atomic_store(&flags[(m + 1) * NBLK + band], TOKEN,
                               __ATOMIC_RELAXED, __HIP_MEMORY_SCOPE_AGENT);

        // ---- off-chain: LDS writeback + register rotation (hidden under the
        // neighbors' poll window; made visible by next sync's [A] barrier) ----
        srows[1][tid] = o0; srows[2][tid] = o1;
        srows[3][tid] = o2; srows[4][tid] = o3;
        s0 = o0; s1 = o1; s2 = o2; s3 = o3;
    }
}

extern "C" void kernel_launch(void* const* d_in, const int* in_sizes, int n_in,
                              void* d_out, int out_size, void* d_ws, size_t ws_size,
                              hipStream_t stream) {
    const float* img = (const float*)d_in[0];
    const int* seeds = (const int*)d_in[1];

    float4* out4 = (float4*)d_out;                              // fp32 final only
    char* ws = (char*)d_ws;
    i32x2* parE = (i32x2*)ws;                                   // 4 MB fp16 even parity
    i32x2* parO = (i32x2*)(ws + 4ull * 1024 * 1024);            // 4 MB fp16 odd parity
    unsigned* flags = (unsigned*)(ws + 8ull * 1024 * 1024);     // 51.2 KB token slots

    rw_init_kernel<<<(FLAGS_N + 255) / 256, 256, 0, stream>>>(flags);
    rw_persist_kernel<<<NBLK, TPB, 0, stream>>>(img, seeds, out4, parE, parO, flags);
}